// Round 1
// 267.638 us; speedup vs baseline: 1.4941x; 1.4941x over previous
//
#include <hip/hip_runtime.h>
#include <math.h>

// Problem constants
#define TOKENS 32768
#define DM 4096
#define NE 64
#define BALW 0.1f

#define TG 64
#define GBLOCKS (TOKENS / TG)  // 512

// ================= Kernel A (primary): 256x64 tile, 8x8/thread =================
// grid = (TOKENS/TM) * SK = 128*4 = 512 blocks -> 2 blocks/CU, 8 waves/CU.
// Per-thread 8m x 8n (64 acc). As k-major [BK][260], Ws k-major [BK][68].
// A-frag: 2x ds_read_b128, 8-lane broadcast, banks {0-3,8-11,16-19,24-27},
// worst 2-way (free). B-frag: 2x ds_read_b128, same structure. 4 b128 reads
// feed 128 FLOP/lane/k = 0.5 B/FLOP (was 0.75 with 8x4 + 4x b32).
#define TM 256
#define BK 32
#define LDSA 260  // 256+4 dwords: 1040 B row stride, 16B-aligned, 4-bank rotate
#define LDSB 68   // 64+4 dwords: 272 B row stride, 16B-aligned

template <int SK>
__global__ __launch_bounds__(256) void gemm_partial_kernel(
    const float* __restrict__ x, const float* __restrict__ w1,
    float* __restrict__ hp) {
  __shared__ float As[BK * LDSA];  // 33.3 KB
  __shared__ float Ws[BK * LDSB];  // 8.7 KB
  const int tid = threadIdx.x;
  const int kz = blockIdx.x % SK;
  const int mb = blockIdx.x / SK;
  const int row0 = mb * TM;
  const int KS = DM / SK;
  const int kbase = kz * KS;
  const int kend = kbase + KS;
  const int m0 = (tid >> 3) * 8;  // 0..248
  const int n0 = (tid & 7) * 8;   // 0..56
  const int tA = tid >> 3;        // 0..31, staging row group
  const int kA = (tid & 7) * 4;   // 0..28, staging k offset

  float acc[8][8];
#pragma unroll
  for (int i = 0; i < 8; ++i)
#pragma unroll
    for (int j = 0; j < 8; ++j) acc[i][j] = 0.f;

  // staging registers: one tile in flight (40 VGPRs)
  float4 ra[8], rw[2];
  const float* xbase = &x[(size_t)(row0 + tA) * DM + kA];
  const float* wbase = &w1[(size_t)tA * DM + kA];

  // prologue: load first tile
#pragma unroll
  for (int it = 0; it < 8; ++it)
    ra[it] = *reinterpret_cast<const float4*>(xbase + (size_t)32 * it * DM + kbase);
#pragma unroll
  for (int q = 0; q < 2; ++q)
    rw[q] = *reinterpret_cast<const float4*>(wbase + (size_t)32 * q * DM + kbase);

  for (int kc = kbase; kc < kend; kc += BK) {
    __syncthreads();  // previous compute done reading LDS
    // store staged tile -> LDS (k-major). 4-way write conflicts only.
#pragma unroll
    for (int it = 0; it < 8; ++it) {
      const int t = tA + 32 * it;
      As[(kA + 0) * LDSA + t] = ra[it].x;
      As[(kA + 1) * LDSA + t] = ra[it].y;
      As[(kA + 2) * LDSA + t] = ra[it].z;
      As[(kA + 3) * LDSA + t] = ra[it].w;
    }
#pragma unroll
    for (int q = 0; q < 2; ++q) {
      const int r = tA + 32 * q;
      Ws[(kA + 0) * LDSB + r] = rw[q].x;
      Ws[(kA + 1) * LDSB + r] = rw[q].y;
      Ws[(kA + 2) * LDSB + r] = rw[q].z;
      Ws[(kA + 3) * LDSB + r] = rw[q].w;
    }
    __syncthreads();
    // issue next tile's global loads early: latency hides under compute
    if (kc + BK < kend) {
#pragma unroll
      for (int it = 0; it < 8; ++it)
        ra[it] = *reinterpret_cast<const float4*>(xbase + (size_t)32 * it * DM +
                                                  (kc + BK));
#pragma unroll
      for (int q = 0; q < 2; ++q)
        rw[q] = *reinterpret_cast<const float4*>(wbase + (size_t)32 * q * DM +
                                                 (kc + BK));
    }
#pragma unroll 8
    for (int k = 0; k < BK; ++k) {
      const float4 a0 = *reinterpret_cast<const float4*>(&As[k * LDSA + m0]);
      const float4 a1 = *reinterpret_cast<const float4*>(&As[k * LDSA + m0 + 4]);
      const float4 b0 = *reinterpret_cast<const float4*>(&Ws[k * LDSB + n0]);
      const float4 b1 = *reinterpret_cast<const float4*>(&Ws[k * LDSB + n0 + 4]);
      const float a[8] = {a0.x, a0.y, a0.z, a0.w, a1.x, a1.y, a1.z, a1.w};
      const float b[8] = {b0.x, b0.y, b0.z, b0.w, b1.x, b1.y, b1.z, b1.w};
#pragma unroll
      for (int i = 0; i < 8; ++i)
#pragma unroll
        for (int j = 0; j < 8; ++j) acc[i][j] = fmaf(a[i], b[j], acc[i][j]);
    }
  }

  float* dst = hp + (size_t)kz * TOKENS * NE;
#pragma unroll
  for (int i = 0; i < 8; ++i) {
    const size_t o = (size_t)(row0 + m0 + i) * NE;
    *reinterpret_cast<float4*>(&dst[o + n0]) =
        make_float4(acc[i][0], acc[i][1], acc[i][2], acc[i][3]);
    *reinterpret_cast<float4*>(&dst[o + n0 + 4]) =
        make_float4(acc[i][4], acc[i][5], acc[i][6], acc[i][7]);
  }
}

// ================= Kernel A (fallback, proven): 128x64 tile, 8x4/thread =====
// Used only if ws_size can't hold SK=4 partials. Identical to previous session.
#define TMF 128
#define BKF 32
#define LDSAF (TMF + 4)  // 132
#define LDSW 33

__global__ __launch_bounds__(256, 2) void gemm_partial_k2(
    const float* __restrict__ x, const float* __restrict__ w1,
    float* __restrict__ hp) {
  __shared__ float As[BKF * LDSAF];
  __shared__ float Ws[NE * LDSW];
  const int tid = threadIdx.x;
  const int mb = blockIdx.x >> 1;
  const int kz = blockIdx.x & 1;
  const int row0 = mb * TMF;
  const int kbase = kz * (DM / 2);
  const int ty = tid >> 4;
  const int tx = tid & 15;
  const int m0 = ty * 8;
  const int n0 = tx * 4;

  float acc[8][4];
#pragma unroll
  for (int i = 0; i < 8; ++i)
#pragma unroll
    for (int j = 0; j < 4; ++j) acc[i][j] = 0.f;

  for (int kc = kbase; kc < kbase + DM / 2; kc += BKF) {
    __syncthreads();
#pragma unroll
    for (int it = 0; it < 4; ++it) {
      const int f = tid + 256 * it;
      const int k4 = f & 7;
      const int t = f >> 3;
      const float4 v = *reinterpret_cast<const float4*>(
          &x[(size_t)(row0 + t) * DM + kc + k4 * 4]);
      As[(k4 * 4 + 0) * LDSAF + t] = v.x;
      As[(k4 * 4 + 1) * LDSAF + t] = v.y;
      As[(k4 * 4 + 2) * LDSAF + t] = v.z;
      As[(k4 * 4 + 3) * LDSAF + t] = v.w;
    }
#pragma unroll
    for (int q = 0; q < 2; ++q) {
      const int f = tid + 256 * q;
      const int c = f & 7;
      const int r = f >> 3;
      const float4 v = *reinterpret_cast<const float4*>(
          &w1[(size_t)r * DM + kc + c * 4]);
      float* d = &Ws[r * LDSW + c * 4];
      d[0] = v.x; d[1] = v.y; d[2] = v.z; d[3] = v.w;
    }
    __syncthreads();
#pragma unroll 8
    for (int k = 0; k < BKF; ++k) {
      const float4 a0 = *reinterpret_cast<const float4*>(&As[k * LDSAF + m0]);
      const float4 a1 =
          *reinterpret_cast<const float4*>(&As[k * LDSAF + m0 + 4]);
      float b[4];
#pragma unroll
      for (int j = 0; j < 4; ++j) b[j] = Ws[(n0 + j) * LDSW + k];
      const float a[8] = {a0.x, a0.y, a0.z, a0.w, a1.x, a1.y, a1.z, a1.w};
#pragma unroll
      for (int i = 0; i < 8; ++i)
#pragma unroll
        for (int j = 0; j < 4; ++j) acc[i][j] = fmaf(a[i], b[j], acc[i][j]);
    }
  }
  float* dst = hp + (size_t)kz * TOKENS * NE;
#pragma unroll
  for (int i = 0; i < 8; ++i) {
    const float4 v = make_float4(acc[i][0], acc[i][1], acc[i][2], acc[i][3]);
    *reinterpret_cast<float4*>(&dst[(size_t)(row0 + m0 + i) * NE + n0]) = v;
  }
}

// ================= Kernel B: gate =================
template <int SK>
__global__ __launch_bounds__(256) void gate_kernel(
    const float* __restrict__ hp, const float* __restrict__ w2,
    const float* __restrict__ noise, float* __restrict__ out_idx,
    float* __restrict__ out_score, float* __restrict__ imp_part,
    float* __restrict__ load_part) {
  __shared__ float hs[TG * 65];
  __shared__ float w2s[NE * 65];
  __shared__ float ls[TG * 66];
  __shared__ float csum[2 * NE];
  __shared__ int hist[NE];
  const int tid = threadIdx.x;
  const int t0 = blockIdx.x * TG;
  if (tid < NE) hist[tid] = 0;

  // stage hs = tanh(sum of SK partials): 64*16 float4s, 4/thread
#pragma unroll
  for (int it = 0; it < 4; ++it) {
    const int f = tid + 256 * it;
    const int c = f & 15;
    const int t = f >> 4;
    const size_t g = (size_t)(t0 + t) * NE + c * 4;
    float4 p = *reinterpret_cast<const float4*>(&hp[g]);
#pragma unroll
    for (int s = 1; s < SK; ++s) {
      const float4 q =
          *reinterpret_cast<const float4*>(&hp[(size_t)s * TOKENS * NE + g]);
      p.x += q.x; p.y += q.y; p.z += q.z; p.w += q.w;
    }
    float* d = &hs[t * 65 + c * 4];
    d[0] = tanhf(p.x);
    d[1] = tanhf(p.y);
    d[2] = tanhf(p.z);
    d[3] = tanhf(p.w);
  }
  // stage w2 [64x64]
#pragma unroll
  for (int it = 0; it < 4; ++it) {
    const int f = tid + 256 * it;
    const int c = f & 15;
    const int r = f >> 4;
    const float4 v =
        *reinterpret_cast<const float4*>(&w2[(size_t)r * NE + c * 4]);
    float* d = &w2s[r * 65 + c * 4];
    d[0] = v.x; d[1] = v.y; d[2] = v.z; d[3] = v.w;
  }
  __syncthreads();

  // phase 1: logits = hs @ w2s^T, 4x4 per thread
  {
    const int m0 = (tid >> 4) * 4;
    const int n0 = (tid & 15) * 4;
    float acc[4][4];
#pragma unroll
    for (int i = 0; i < 4; ++i)
#pragma unroll
      for (int j = 0; j < 4; ++j) acc[i][j] = 0.f;
#pragma unroll 8
    for (int k = 0; k < NE; ++k) {
      float a[4], b[4];
#pragma unroll
      for (int i = 0; i < 4; ++i) a[i] = hs[(m0 + i) * 65 + k];
#pragma unroll
      for (int j = 0; j < 4; ++j) b[j] = w2s[(n0 + j) * 65 + k];
#pragma unroll
      for (int i = 0; i < 4; ++i)
#pragma unroll
        for (int j = 0; j < 4; ++j) acc[i][j] = fmaf(a[i], b[j], acc[i][j]);
    }
#pragma unroll
    for (int i = 0; i < 4; ++i)
#pragma unroll
      for (int j = 0; j < 4; ++j) ls[(m0 + i) * 66 + n0 + j] = acc[i][j];
  }
  __syncthreads();

  // phase 2: per-token softmax + gumbel argmax (1 wave)
  if (tid < TG) {
    const int t = tid;
    float mx = -INFINITY, best = -INFINITY;
    int bi = 0;
    for (int e = 0; e < NE; ++e) {
      const float l = ls[t * 66 + e];
      mx = fmaxf(mx, l);
      const float g = l + noise[(size_t)(t0 + t) * NE + e];
      if (g > best) { best = g; bi = e; }
    }
    float s = 0.f;
    for (int e = 0; e < NE; ++e) {
      const float ex = expf(ls[t * 66 + e] - mx);
      s += ex;
      ls[t * 66 + e] = ex;
    }
    const float inv = 1.f / s;
    for (int e = 0; e < NE; ++e) ls[t * 66 + e] *= inv;
    out_idx[t0 + t] = (float)bi;
    out_score[t0 + t] = best;
    atomicAdd(&hist[bi], 1);
  }
  __syncthreads();

  // phase 3: column sums of scores
  if (tid < 128) {
    const int e = tid & 63;
    const int half = tid >> 6;
    float s = 0.f;
    for (int r = half * 32; r < half * 32 + 32; ++r) s += ls[r * 66 + e];
    csum[half * NE + e] = s;
  }
  __syncthreads();
  if (tid < NE) {
    imp_part[(size_t)blockIdx.x * NE + tid] = csum[tid] + csum[NE + tid];
    load_part[(size_t)blockIdx.x * NE + tid] = (float)hist[tid];
  }
}

// ================= Kernel C: finalize =================
__global__ void finalize_kernel(const float* __restrict__ imp_part,
                                const float* __restrict__ load_part,
                                float* __restrict__ out) {
  const int e = threadIdx.x;  // 64 threads, 1 wave
  float imp = 0.f, ld = 0.f;
  for (int b = 0; b < GBLOCKS; ++b) {
    imp += imp_part[(size_t)b * NE + e];
    ld += load_part[(size_t)b * NE + e];
  }
  const float imp_mean = imp / (float)TOKENS;
  const float load_mean = ld / (float)TOKENS;
  out[2 * TOKENS + 1 + e] = load_mean;
  out[2 * TOKENS + 1 + NE + e] = imp_mean;
  float prod = imp_mean * load_mean;
#pragma unroll
  for (int off = 32; off > 0; off >>= 1) prod += __shfl_down(prod, off);
  if (e == 0) out[2 * TOKENS] = (float)NE * prod * BALW;
}

// ================= launch =================
extern "C" void kernel_launch(void* const* d_in, const int* in_sizes, int n_in,
                              void* d_out, int out_size, void* d_ws,
                              size_t ws_size, hipStream_t stream) {
  const float* x = (const float*)d_in[0];
  const float* w1 = (const float*)d_in[1];
  const float* w2 = (const float*)d_in[2];
  const float* noise = (const float*)d_in[3];
  float* out = (float*)d_out;

  const size_t part_elems = (size_t)2 * GBLOCKS * NE;
  const size_t need4 =
      ((size_t)4 * TOKENS * NE + part_elems) * sizeof(float);  // ~33.8 MB

  if (ws_size == 0 || ws_size >= need4) {
    // primary: SPLITK=4, 256x64 tiles
    float* hp = (float*)d_ws;
    float* imp_part = hp + (size_t)4 * TOKENS * NE;
    float* load_part = imp_part + (size_t)GBLOCKS * NE;
    hipLaunchKernelGGL((gemm_partial_kernel<4>), dim3((TOKENS / TM) * 4),
                       dim3(256), 0, stream, x, w1, hp);
    hipLaunchKernelGGL((gate_kernel<4>), dim3(GBLOCKS), dim3(256), 0, stream,
                       hp, w2, noise, out, out + TOKENS, imp_part, load_part);
    hipLaunchKernelGGL(finalize_kernel, dim3(1), dim3(64), 0, stream, imp_part,
                       load_part, out);
  } else {
    // fallback: SPLITK=2, previous proven kernel
    float* hp = (float*)d_ws;
    float* imp_part = hp + (size_t)2 * TOKENS * NE;
    float* load_part = imp_part + (size_t)GBLOCKS * NE;
    hipLaunchKernelGGL(gemm_partial_k2, dim3((TOKENS / TMF) * 2), dim3(256), 0,
                       stream, x, w1, hp);
    hipLaunchKernelGGL((gate_kernel<2>), dim3(GBLOCKS), dim3(256), 0, stream,
                       hp, w2, noise, out, out + TOKENS, imp_part, load_part);
    hipLaunchKernelGGL(finalize_kernel, dim3(1), dim3(64), 0, stream, imp_part,
                       load_part, out);
  }
}